// Round 6
// baseline (211.180 us; speedup 1.0000x reference)
//
#include <hip/hip_runtime.h>
#include <math.h>
#include <stdint.h>

typedef _Float16 half8 __attribute__((ext_vector_type(8)));
typedef float floatx4 __attribute__((ext_vector_type(4)));

#define NTOK   16384
#define DIM    2048
#define NEXP   64
#define MB     64                  // tokens per block
#define NBLK   (NTOK / MB)         // 256 blocks
#define THREADS 512
#define KC     64                  // K per chunk
#define NCHUNK (DIM / KC)          // 32
#define WSW_H8 16384               // half8 slots per split (64 ksteps x 4 tg x 64 lanes)
#define WSW_BYTES (2 * WSW_H8 * 16)

#define A_BYTES 16384              // per buffer: 64 rows x 256 B
#define B_BYTES 16384              // per buffer: 2 splits x 8 KB
#define AOFF(b) ((b) * A_BYTES)
#define BOFF(b) (2 * A_BYTES + (b) * B_BYTES)
#define SMEM_BYTES (2 * A_BYTES + 2 * B_BYTES)   // 65536

// ---- prep: split W (fp32) into f16 hi + scaled-lo (2^11), B-fragment order:
// slot(sg,tg,lane) = (sg*4+tg)*64+lane holds W[tg*16+(lane&15)][sg*32+(lane>>4)*8 + 0..7]
__global__ void wprep_kernel(const float* __restrict__ W, _Float16* __restrict__ wsw) {
    const int id   = blockIdx.x * blockDim.x + threadIdx.x; // 0..16383
    const int lane = id & 63;
    const int tg   = (id >> 6) & 3;
    const int sg   = id >> 8;                               // 0..63
    const int e    = tg * 16 + (lane & 15);
    const int k    = sg * 32 + (lane >> 4) * 8;
    const float* src = W + (size_t)e * DIM + k;
    half8 h, l;
#pragma unroll
    for (int j = 0; j < 8; j++) {
        const float v  = src[j];
        const _Float16 hh = (_Float16)v;
        h[j] = hh;
        l[j] = (_Float16)((v - (float)hh) * 2048.0f);
    }
    const size_t slot = (size_t)(sg * 4 + tg) * 64 + lane;
    ((half8*)wsw)[slot]          = h;
    ((half8*)wsw)[WSW_H8 + slot] = l;
}

__device__ __forceinline__ void split_a(const float4& v0, const float4& v1,
                                        half8& hi, half8& lo) {
    const float av[8] = {v0.x, v0.y, v0.z, v0.w, v1.x, v1.y, v1.z, v1.w};
#pragma unroll
    for (int j = 0; j < 8; j++) {
        const _Float16 hh = (_Float16)av[j];
        hi[j] = hh;
        lo[j] = (_Float16)((av[j] - (float)hh) * 2048.0f);
    }
}

// async global->LDS DMA, 16 B/lane. LDS dest = uniform base + lane*16 (HW rule).
__device__ __forceinline__ void dma16(const void* g, const char* l) {
    __builtin_amdgcn_global_load_lds(
        (const __attribute__((address_space(1))) unsigned int*)(uintptr_t)g,
        (__attribute__((address_space(3))) unsigned int*)(uintptr_t)l,
        16, 0, 0);
}

template <bool USE_WS>
__global__ __launch_bounds__(THREADS, 2)
void gating_lds_kernel(const float* __restrict__ x, const float* __restrict__ W,
                       const _Float16* __restrict__ wsw, const float* __restrict__ bias,
                       float* __restrict__ out)
{
    __shared__ char smem[SMEM_BYTES];

    const int tid  = threadIdx.x;
    const int lane = tid & 63;
    const int w    = tid >> 6;          // 0..7
    const int mt   = w & 3;             // m-tile (16 tokens): 0..3
    const int nh   = w >> 2;            // n-half (2 expert tiles): 0..1
    const int col  = lane & 15;
    const int quad = lane >> 4;
    const int tok0 = blockIdx.x * MB;
    const int m    = mt * 16 + col;     // this lane's token row (0..63)

    // ---- A DMA: issue a = w*2+i (0..15) covers rows a*4..a*4+3 (256 B/row).
    // Gather-side XOR swizzle within 128 B: LDS piece pz holds global piece
    // (pz&8)|((pz&7)^(row&7))  => frag ds_reads land on distinct banks.
    const float* gA[2];
    unsigned     lA[2];
#pragma unroll
    for (int i = 0; i < 2; i++) {
        const int a   = w * 2 + i;
        const int row = a * 4 + quad;
        const int pz  = lane & 15;
        const int gp  = (pz & 8) | ((pz & 7) ^ (row & 7));
        gA[i] = x + (size_t)(tok0 + row) * DIM + gp * 4;
        lA[i] = (unsigned)(a * 1024);
    }
    // ---- B DMA: verbatim contiguous copy of this chunk's 8 KB per split.
    const char* gB[2];
    unsigned    lB[2];
    if constexpr (USE_WS) {
#pragma unroll
        for (int j = 0; j < 2; j++) {
            gB[j] = (const char*)wsw + (size_t)j * (WSW_H8 * 16) + w * 1024 + lane * 16;
            lB[j] = (unsigned)(j * 8192 + w * 1024);
        }
    }

    floatx4 accm[2] = {{0,0,0,0},{0,0,0,0}};
    floatx4 accl[2] = {{0,0,0,0},{0,0,0,0}};

    // prologue: DMA chunk 0 into buffer 0
#pragma unroll
    for (int i = 0; i < 2; i++) dma16(gA[i], smem + AOFF(0) + lA[i]);
    if constexpr (USE_WS) {
#pragma unroll
        for (int j = 0; j < 2; j++) dma16(gB[j], smem + BOFF(0) + lB[j]);
    }

#pragma unroll 2
    for (int c = 0; c < NCHUNK; ++c) {
        __syncthreads();    // vmcnt(0) drain: chunk c staged for all waves
        if (c + 1 < NCHUNK) {
            const int nb = (c + 1) & 1;
#pragma unroll
            for (int i = 0; i < 2; i++)
                dma16(gA[i] + (size_t)(c + 1) * KC, smem + AOFF(nb) + lA[i]);
            if constexpr (USE_WS) {
#pragma unroll
                for (int j = 0; j < 2; j++)
                    dma16(gB[j] + (size_t)(c + 1) * 8192, smem + BOFF(nb) + lB[j]);
            }
        }
        const char* Ab = smem + AOFF(c & 1);
        const char* Bb = smem + BOFF(c & 1);
#pragma unroll
        for (int s = 0; s < 2; s++) {
            const float4 v0 = *(const float4*)(Ab + m * 256 + (8 * s + ((2 * quad + 0) ^ (m & 7))) * 16);
            const float4 v1 = *(const float4*)(Ab + m * 256 + (8 * s + ((2 * quad + 1) ^ (m & 7))) * 16);
            half8 ah, alo;
            split_a(v0, v1, ah, alo);
#pragma unroll
            for (int t = 0; t < 2; t++) {
                const int tg = nh * 2 + t;
                half8 bh, bl;
                if constexpr (USE_WS) {
                    bh = *(const half8*)(Bb + (s * 4 + tg) * 1024 + lane * 16);
                    bl = *(const half8*)(Bb + 8192 + (s * 4 + tg) * 1024 + lane * 16);
                } else {
                    const float* wr = W + (size_t)(tg * 16 + col) * DIM + c * KC + s * 32 + quad * 8;
                    split_a(*(const float4*)wr, *(const float4*)(wr + 4), bh, bl);
                }
                accm[t] = __builtin_amdgcn_mfma_f32_16x16x32_f16(ah,  bh, accm[t], 0, 0, 0);
                accl[t] = __builtin_amdgcn_mfma_f32_16x16x32_f16(ah,  bl, accl[t], 0, 0, 0);
                accl[t] = __builtin_amdgcn_mfma_f32_16x16x32_f16(alo, bh, accl[t], 0, 0, 0);
            }
        }
    }

    __syncthreads();            // staging reads done; alias logits onto smem
    float* lg = (float*)smem;   // [64 tok][65] stride-65 (16.6 KB < 64 KB)
    const float inv = 1.0f / 2048.0f;
#pragma unroll
    for (int t = 0; t < 2; t++) {
        const int tg = nh * 2 + t;
#pragma unroll
        for (int r = 0; r < 4; r++) {
            // C/D: row = quad*4+r, col = lane&15  [m89-verified]
            lg[(mt * 16 + quad * 4 + r) * 65 + tg * 16 + col] = accm[t][r] + accl[t][r] * inv;
        }
    }
    __syncthreads();

    if (tid < MB) {
        const int t = tid;
        float v0 = -INFINITY, v1 = -INFINITY;
        int   i0 = 0, i1 = 0;
        for (int e = 0; e < NEXP; e++) {
            const float v = lg[t * 65 + e] + bias[e];
            if (v > v0) { v1 = v0; i1 = i0; v0 = v; i0 = e; }
            else if (v > v1) { v1 = v; i1 = e; }
        }
        const float e1 = expf(v1 - v0);   // v1 <= v0: stable
        const float sden = 1.f + e1;
        const int   g  = tok0 + t;
        out[2 * g + 0] = 1.f / sden;
        out[2 * g + 1] = e1 / sden;
        out[2 * NTOK + 2 * g + 0] = (float)i0;
        out[2 * NTOK + 2 * g + 1] = (float)i1;
    }
}

extern "C" void kernel_launch(void* const* d_in, const int* in_sizes, int n_in,
                              void* d_out, int out_size, void* d_ws, size_t ws_size,
                              hipStream_t stream) {
    const float* x    = (const float*)d_in[0];
    const float* W    = (const float*)d_in[1];
    const float* bias = (const float*)d_in[2];
    float*       out  = (float*)d_out;
    _Float16*    wsw  = (_Float16*)d_ws;

    if (ws_size >= (size_t)WSW_BYTES) {
        hipLaunchKernelGGL(wprep_kernel, dim3(64), dim3(256), 0, stream, (const float*)d_in[1], wsw);
        hipLaunchKernelGGL((gating_lds_kernel<true>), dim3(NBLK), dim3(THREADS), 0, stream,
                           x, W, wsw, bias, out);
    } else {
        hipLaunchKernelGGL((gating_lds_kernel<false>), dim3(NBLK), dim3(THREADS), 0, stream,
                           x, W, wsw, bias, out);
    }
}